// Round 5
// baseline (105.238 us; speedup 1.0000x reference)
//
#include <hip/hip_runtime.h>

// Problem constants (fixed by reference setup_inputs)
#define Bn 32
#define Cn 512
#define HWn 4096   // 64*64
#define Kn 256     // C/2

typedef float vfloat4 __attribute__((ext_vector_type(4)));

__device__ __forceinline__ vfloat4 nt_load(const vfloat4* p) {
    return __builtin_nontemporal_load(p);
}

// ---------------------------------------------------------------------------
// Kernel 1: per-(b,c) mean over H*W. One wave per 16 KiB channel slice:
// 64 lanes x 16 dwordx4 non-temporal loads (stream, no reuse), double
// accumulate, 6-step shfl_xor butterfly. Double keeps the fp32-rounded
// result order-independent (top-k rank depends on it).
// ---------------------------------------------------------------------------
__global__ __launch_bounds__(256) void eca_mean_kernel(
    const float* __restrict__ x, float* __restrict__ y) {
    int slice = (blockIdx.x << 2) + (threadIdx.x >> 6);  // grid 1024, 4 waves
    int lane = threadIdx.x & 63;
    const vfloat4* p = (const vfloat4*)(x + (size_t)slice * HWn);
    double s = 0.0;
#pragma unroll
    for (int i = 0; i < 16; ++i) {
        vfloat4 v = nt_load(&p[lane + (i << 6)]);
        s += ((double)v.x + (double)v.y) + ((double)v.z + (double)v.w);
    }
#pragma unroll
    for (int m = 32; m; m >>= 1) s += __shfl_xor(s, m, 64);
    if (lane == 0) y[slice] = (float)(s * (1.0 / 4096.0));
}

// ---------------------------------------------------------------------------
// Kernel 2: conv1d(pad=1) + sigmoid + top-k rank per batch. One block per
// batch, 512 threads (one per channel). Rank-by-counting reproduces
// lax.top_k's descending order with stable (lower-index-first) ties.
// Conv replicated as numpy does it: separate fp32 mul/adds, left-to-right,
// no FMA contraction (__fmul_rn/__fadd_rn).
// ---------------------------------------------------------------------------
__global__ __launch_bounds__(Cn) void eca_topk_kernel(
    const float* __restrict__ y, const float* __restrict__ w,
    int* __restrict__ idx) {
    int b = blockIdx.x;
    int c = threadIdx.x;  // 0 .. Cn-1
    __shared__ float sc[Cn];

    float w0 = w[0], w1 = w[1], w2 = w[2];
    float ym1 = (c == 0) ? 0.0f : y[b * Cn + c - 1];
    float y0 = y[b * Cn + c];
    float yp1 = (c == Cn - 1) ? 0.0f : y[b * Cn + c + 1];

    float s = __fmul_rn(w0, ym1);
    s = __fadd_rn(s, __fmul_rn(w1, y0));
    s = __fadd_rn(s, __fmul_rn(w2, yp1));
    float sig = 1.0f / (1.0f + expf(-s));

    sc[c] = sig;
    __syncthreads();

    int rank = 0;
    for (int j = 0; j < Cn; ++j) {
        float o = sc[j];  // same address across lanes -> LDS broadcast
        rank += (o > sig || (o == sig && j < c)) ? 1 : 0;
    }
    if (rank < Kn) idx[b * Kn + rank] = c;
}

// ---------------------------------------------------------------------------
// Kernel 3: gather selected channel slices. One block per (b, rank) output
// slice; uniform index load, then coalesced float4 copy of 16 KB.
// Non-temporal on BOTH sides: src slices are read exactly once, dst is
// write-only — neither should allocate in L2/L3.
// ---------------------------------------------------------------------------
__global__ __launch_bounds__(256) void eca_gather_kernel(
    const float* __restrict__ x, const int* __restrict__ idx,
    float* __restrict__ out) {
    int bj = blockIdx.x;  // b*Kn + j
    int b = bj >> 8;      // Kn == 256
    int c = idx[bj];
    const vfloat4* src = (const vfloat4*)(x + ((size_t)b * Cn + c) * HWn);
    vfloat4* dst = (vfloat4*)(out + (size_t)bj * HWn);
    int t = threadIdx.x;

    vfloat4 v[4];
#pragma unroll
    for (int i = 0; i < 4; ++i) v[i] = nt_load(&src[t + i * 256]);
#pragma unroll
    for (int i = 0; i < 4; ++i)
        __builtin_nontemporal_store(v[i], &dst[t + i * 256]);
}

extern "C" void kernel_launch(void* const* d_in, const int* in_sizes, int n_in,
                              void* d_out, int out_size, void* d_ws,
                              size_t ws_size, hipStream_t stream) {
    const float* x = (const float*)d_in[0];
    const float* w = (const float*)d_in[1];
    float* out = (float*)d_out;

    float* y = (float*)d_ws;                                  // Bn*Cn floats
    int* idx = (int*)((char*)d_ws + Bn * Cn * sizeof(float)); // Bn*Kn ints

    eca_mean_kernel<<<(Bn * Cn) / 4, 256, 0, stream>>>(x, y);
    eca_topk_kernel<<<Bn, Cn, 0, stream>>>(y, w, idx);
    eca_gather_kernel<<<Bn * Kn, 256, 0, stream>>>(x, idx, out);
}

// Round 6
// 98.247 us; speedup vs baseline: 1.0712x; 1.0712x over previous
//
#include <hip/hip_runtime.h>

// Problem constants (fixed by reference setup_inputs)
#define Bn 32
#define Cn 512
#define HWn 4096   // 64*64
#define Kn 256     // C/2

typedef float vfloat4 __attribute__((ext_vector_type(4)));

// ---------------------------------------------------------------------------
// Kernel 1: per-(b,c) mean over H*W. One wave per 16 KiB channel slice:
// 64 lanes x 16 dwordx4 TEMPORAL loads (nt loads measured -7us, round 5),
// double accumulate, 6-step shfl_xor butterfly. Double keeps the
// fp32-rounded result order-independent (top-k rank depends on it).
// ---------------------------------------------------------------------------
__global__ __launch_bounds__(256) void eca_mean_kernel(
    const float* __restrict__ x, float* __restrict__ y) {
    int slice = (blockIdx.x << 2) + (threadIdx.x >> 6);
    int lane = threadIdx.x & 63;
    const vfloat4* p = (const vfloat4*)(x + (size_t)slice * HWn);
    double s = 0.0;
#pragma unroll
    for (int i = 0; i < 16; ++i) {
        vfloat4 v = p[lane + (i << 6)];
        s += ((double)v.x + (double)v.y) + ((double)v.z + (double)v.w);
    }
#pragma unroll
    for (int m = 32; m; m >>= 1) s += __shfl_xor(s, m, 64);
    if (lane == 0) y[slice] = (float)(s * (1.0 / 4096.0));
}

// ---------------------------------------------------------------------------
// Kernel 2: conv1d(pad=1) + sigmoid + top-k rank per batch. One block per
// batch, 512 threads (one per channel). Rank-by-counting reproduces
// lax.top_k's descending order with stable (lower-index-first) ties.
// Conv replicated as numpy does it: separate fp32 mul/adds, left-to-right,
// no FMA contraction. Rank loop reads LDS as float4 (ds_read_b128
// broadcast) — 128 iterations instead of 512, identical comparisons.
// ---------------------------------------------------------------------------
__global__ __launch_bounds__(Cn) void eca_topk_kernel(
    const float* __restrict__ y, const float* __restrict__ w,
    int* __restrict__ idx) {
    int b = blockIdx.x;
    int c = threadIdx.x;  // 0 .. Cn-1
    __shared__ float sc[Cn];

    float w0 = w[0], w1 = w[1], w2 = w[2];
    float ym1 = (c == 0) ? 0.0f : y[b * Cn + c - 1];
    float y0 = y[b * Cn + c];
    float yp1 = (c == Cn - 1) ? 0.0f : y[b * Cn + c + 1];

    float s = __fmul_rn(w0, ym1);
    s = __fadd_rn(s, __fmul_rn(w1, y0));
    s = __fadd_rn(s, __fmul_rn(w2, yp1));
    float sig = 1.0f / (1.0f + expf(-s));

    sc[c] = sig;
    __syncthreads();

    const vfloat4* sc4 = (const vfloat4*)sc;
    int rank = 0;
#pragma unroll 4
    for (int q = 0; q < Cn / 4; ++q) {
        vfloat4 o = sc4[q];  // same address across lanes -> LDS broadcast
        int j = q << 2;
        rank += (o.x > sig || (o.x == sig && (j + 0) < c)) ? 1 : 0;
        rank += (o.y > sig || (o.y == sig && (j + 1) < c)) ? 1 : 0;
        rank += (o.z > sig || (o.z == sig && (j + 2) < c)) ? 1 : 0;
        rank += (o.w > sig || (o.w == sig && (j + 3) < c)) ? 1 : 0;
    }
    if (rank < Kn) idx[b * Kn + rank] = c;
}

// ---------------------------------------------------------------------------
// Kernel 3: gather selected channel slices. One block per (b, rank) output
// slice; uniform index load, then coalesced float4 copy of 16 KB.
// Temporal loads (nt loads regressed); NON-TEMPORAL stores (write-only
// output, never re-read; measured +2.7us in round 3).
// ---------------------------------------------------------------------------
__global__ __launch_bounds__(256) void eca_gather_kernel(
    const float* __restrict__ x, const int* __restrict__ idx,
    float* __restrict__ out) {
    int bj = blockIdx.x;  // b*Kn + j
    int b = bj >> 8;      // Kn == 256
    int c = idx[bj];
    const vfloat4* src = (const vfloat4*)(x + ((size_t)b * Cn + c) * HWn);
    vfloat4* dst = (vfloat4*)(out + (size_t)bj * HWn);
    int t = threadIdx.x;

    vfloat4 v[4];
#pragma unroll
    for (int i = 0; i < 4; ++i) v[i] = src[t + i * 256];
#pragma unroll
    for (int i = 0; i < 4; ++i)
        __builtin_nontemporal_store(v[i], &dst[t + i * 256]);
}

extern "C" void kernel_launch(void* const* d_in, const int* in_sizes, int n_in,
                              void* d_out, int out_size, void* d_ws,
                              size_t ws_size, hipStream_t stream) {
    const float* x = (const float*)d_in[0];
    const float* w = (const float*)d_in[1];
    float* out = (float*)d_out;

    float* y = (float*)d_ws;                                  // Bn*Cn floats
    int* idx = (int*)((char*)d_ws + Bn * Cn * sizeof(float)); // Bn*Kn ints

    eca_mean_kernel<<<(Bn * Cn) / 4, 256, 0, stream>>>(x, y);
    eca_topk_kernel<<<Bn, Cn, 0, stream>>>(y, w, idx);
    eca_gather_kernel<<<Bn * Kn, 256, 0, stream>>>(x, idx, out);
}